// Round 1
// baseline (1408.368 us; speedup 1.0000x reference)
//
#include <hip/hip_runtime.h>
#include <hip/hip_bf16.h>
#include <math.h>

#define IGNORE_INDEX (-100)
#define BETA 0.1f

// Problem constants (B=8, S=512, H=4096, V=32000)
constexpr int Mdim = 8 * 512;   // 4096 tokens
constexpr int Kdim = 4096;      // hidden
constexpr int Ndim = 32000;     // vocab
constexpr int BM = 128, BN = 128;
constexpr int BK8 = 128;        // K per stage in fp8 path (one mfma-K)
constexpr int MT = Mdim / BM;   // 32 m-tiles
constexpr int NT = Ndim / BN;   // 250 n-tiles

typedef __bf16 bf16x8 __attribute__((ext_vector_type(8)));
typedef __bf16 bf16x4 __attribute__((ext_vector_type(4)));
typedef float  floatx4 __attribute__((ext_vector_type(4)));
typedef int    v8i __attribute__((ext_vector_type(8)));
typedef int    v4i __attribute__((ext_vector_type(4)));

#define GPTR(p) ((const __attribute__((address_space(1))) void*)(p))
#define LPTR(p) ((__attribute__((address_space(3))) void*)(p))

// fp32 -> fp8 e4m3 via HW v_cvt_pk_fp8_f32.
// Lane-contiguous: thread t handles float4 #t (16 B/lane read, 4 B/lane write),
// grid-stride. This is the m13 6.29 TB/s coalescing pattern; the previous
// 16-elems/thread layout had a 64 B inter-lane stride and ran at ~1.1 TB/s.
__global__ void cvt_f32_fp8(const float4* __restrict__ src, uint* __restrict__ dst, long n4) {
    long stride = (long)gridDim.x * blockDim.x;
    for (long i = (long)blockIdx.x * blockDim.x + threadIdx.x; i < n4; i += stride) {
        float4 a = src[i];
        int r = __builtin_amdgcn_cvt_pk_fp8_f32(a.x, a.y, 0, false);
        r     = __builtin_amdgcn_cvt_pk_fp8_f32(a.z, a.w, r, true);
        dst[i] = (uint)r;
    }
}

// MX-fp8 GEMM (unit E8M0 scales = plain fp8 matmul at the 4.6 PF MX rate) + fused
// softmax-stat epilogue. A = x8 (M x K fp8, K-contig), B = w8 (N x K fp8).
// LDS layout XOR-swizzled: LDS[row][c] = G[row][c ^ (row&7)] (16B chunks), applied on the
// GLOBAL side so global_load_lds's (base + lane*16) scatter stays legal. Fragment reads
// then spread uniformly over all 8 chunk groups -> conflict-optimal.
__global__ __launch_bounds__(256, 2)
void dpo_gemm_fp8(const unsigned char* __restrict__ x8, const unsigned char* __restrict__ w8,
                  const int* __restrict__ target,
                  float* __restrict__ sumexp, float* __restrict__ sumlog,
                  float* __restrict__ tgtlogit)
{
    __shared__ unsigned char As[BM * BK8];   // 16 KB
    __shared__ unsigned char Bs[BN * BK8];   // 16 KB
    __shared__ int tgt_s[BM];

    const int tid  = threadIdx.x;
    const int lane = tid & 63;
    const int wid  = tid >> 6;
    const int wm   = wid & 1;        // wave row (0..1) -> 64 rows
    const int wn   = wid >> 1;       // wave col (0..1) -> 64 cols
    const int bid  = blockIdx.x;
    const int m0   = (bid & (MT - 1)) * BM;   // m-tile fastest (weight LLC reuse)
    const int n0   = (bid / MT) * BN;

    if (tid < BM) tgt_s[tid] = target[m0 + tid];

    floatx4 acc[4][4] = {};

    const int qr = lane >> 4;   // quad 0..3
    const int cr = lane & 15;

    // staging geometry: wave wid, issue i in {0..3}: lane l -> row = i*32 + wid*8 + (l>>3),
    // global 16B chunk = (l&7) ^ (l>>3)  [row&7 == l>>3 since i*32+wid*8 is mult of 8].
    const int srow   = lane >> 3;               // 0..7
    const int schunk = (lane & 7) ^ srow;       // swizzled chunk
    const unsigned char* xg = x8 + (size_t)(m0 + wid * 8 + srow) * Kdim + schunk * 16;
    const unsigned char* wg = w8 + (size_t)(n0 + wid * 8 + srow) * Kdim + schunk * 16;
    unsigned char* As_w = As + wid * 1024;   // bytes; issue i at +i*4096
    unsigned char* Bs_w = Bs + wid * 1024;

    for (int k0 = 0; k0 < Kdim; k0 += BK8) {
        __syncthreads();   // previous iter's fragment reads complete before overwrite
        #pragma unroll
        for (int i = 0; i < 4; ++i) {
            __builtin_amdgcn_global_load_lds(GPTR(xg + k0 + (size_t)i * 32 * Kdim),
                                             LPTR(As_w + i * 4096), 16, 0, 0);
            __builtin_amdgcn_global_load_lds(GPTR(wg + k0 + (size_t)i * 32 * Kdim),
                                             LPTR(Bs_w + i * 4096), 16, 0, 0);
        }
        __syncthreads();

        // Fragments: A[m=lane&15][k=quad*32+j], j=0..31 (8 dwords). Global k-chunks 2q,2q+1
        // live at LDS chunks (2q)^s, (2q+1)^s with s = row&7 = cr&7.
        const int s  = cr & 7;
        const int c0 = (2 * qr) ^ s;       // LDS chunk holding k [q*32 .. q*32+15]
        const int c1 = (2 * qr + 1) ^ s;   // LDS chunk holding k [q*32+16 .. q*32+31]

        v8i afrag[4], bfrag[4];
        #pragma unroll
        for (int mi = 0; mi < 4; ++mi) {
            const int base = (wm * 64 + mi * 16 + cr) * BK8;
            v4i lo = *(const v4i*)&As[base + c0 * 16];
            v4i hi = *(const v4i*)&As[base + c1 * 16];
            afrag[mi] = __builtin_shufflevector(lo, hi, 0, 1, 2, 3, 4, 5, 6, 7);
        }
        #pragma unroll
        for (int ni = 0; ni < 4; ++ni) {
            const int base = (wn * 64 + ni * 16 + cr) * BK8;
            v4i lo = *(const v4i*)&Bs[base + c0 * 16];
            v4i hi = *(const v4i*)&Bs[base + c1 * 16];
            bfrag[ni] = __builtin_shufflevector(lo, hi, 0, 1, 2, 3, 4, 5, 6, 7);
        }

        #pragma unroll
        for (int mi = 0; mi < 4; ++mi)
            #pragma unroll
            for (int ni = 0; ni < 4; ++ni)
                acc[mi][ni] = __builtin_amdgcn_mfma_scale_f32_16x16x128_f8f6f4(
                    afrag[mi], bfrag[ni], acc[mi][ni],
                    0 /*cbsz: A=fp8 e4m3*/, 0 /*blgp: B=fp8 e4m3*/,
                    0, 0x7F7F7F7F,   // scale_a opsel, unit scales (E8M0 127 = 1.0)
                    0, 0x7F7F7F7F);  // scale_b
    }

    // Epilogue: C/D layout col=lane&15, row=(lane>>4)*4+reg (shape-determined, m121-128).
    #pragma unroll
    for (int mi = 0; mi < 4; ++mi) {
        #pragma unroll
        for (int reg = 0; reg < 4; ++reg) {
            const int lrow = wm * 64 + mi * 16 + qr * 4 + reg;
            const int grow = m0 + lrow;
            const int t = tgt_s[lrow];
            float se = 0.f, sl = 0.f;
            #pragma unroll
            for (int ni = 0; ni < 4; ++ni) {
                float v = acc[mi][ni][reg];
                int gcol = n0 + wn * 64 + ni * 16 + cr;
                if (t == gcol) tgtlogit[grow] = v;   // unique owner globally
                se += __expf(v);
                sl += v;
            }
            #pragma unroll
            for (int st = 1; st < 16; st <<= 1) {
                se += __shfl_xor(se, st, 64);
                sl += __shfl_xor(sl, st, 64);
            }
            if (cr == 0) {
                atomicAdd(&sumexp[grow], se);
                atomicAdd(&sumlog[grow], sl);
            }
        }
    }
}

// Fallback (ws too small): fp32-staged bf16 GEMM with the same swizzled 1D grid.
__global__ __launch_bounds__(256, 2)
void dpo_gemm_f32(const float* __restrict__ x, const float* __restrict__ w,
                  const int* __restrict__ target,
                  float* __restrict__ sumexp, float* __restrict__ sumlog,
                  float* __restrict__ tgtlogit)
{
    constexpr int BK = 32;
    constexpr int LDA = 40;
    __shared__ __bf16 As[BM * LDA];
    __shared__ __bf16 Bs[BN * LDA];
    __shared__ int tgt_s[BM];

    const int tid  = threadIdx.x;
    const int lane = tid & 63;
    const int wid  = tid >> 6;
    const int wm   = wid & 1;
    const int wn   = wid >> 1;
    const int bid  = blockIdx.x;
    const int m0   = (bid & (MT - 1)) * BM;
    const int n0   = (bid / MT) * BN;

    if (tid < BM) tgt_s[tid] = target[m0 + tid];

    floatx4 acc[4][4] = {};
    const int qr = lane >> 4;
    const int cr = lane & 15;

    for (int k0 = 0; k0 < Kdim; k0 += BK) {
        __syncthreads();
        #pragma unroll
        for (int i = 0; i < 4; ++i) {
            int idx = tid + i * 256;
            int row = idx >> 3;
            int c4  = (idx & 7) * 4;
            float4 v = *(const float4*)(x + (size_t)(m0 + row) * Kdim + k0 + c4);
            bf16x4 p;
            p[0] = (__bf16)v.x; p[1] = (__bf16)v.y; p[2] = (__bf16)v.z; p[3] = (__bf16)v.w;
            *(bf16x4*)&As[row * LDA + c4] = p;
        }
        #pragma unroll
        for (int i = 0; i < 4; ++i) {
            int idx = tid + i * 256;
            int row = idx >> 3;
            int c4  = (idx & 7) * 4;
            float4 v = *(const float4*)(w + (size_t)(n0 + row) * Kdim + k0 + c4);
            bf16x4 p;
            p[0] = (__bf16)v.x; p[1] = (__bf16)v.y; p[2] = (__bf16)v.z; p[3] = (__bf16)v.w;
            *(bf16x4*)&Bs[row * LDA + c4] = p;
        }
        __syncthreads();

        bf16x8 afrag[4], bfrag[4];
        #pragma unroll
        for (int mi = 0; mi < 4; ++mi)
            afrag[mi] = *(const bf16x8*)&As[(wm * 64 + mi * 16 + cr) * LDA + qr * 8];
        #pragma unroll
        for (int ni = 0; ni < 4; ++ni)
            bfrag[ni] = *(const bf16x8*)&Bs[(wn * 64 + ni * 16 + cr) * LDA + qr * 8];

        #pragma unroll
        for (int mi = 0; mi < 4; ++mi)
            #pragma unroll
            for (int ni = 0; ni < 4; ++ni)
                acc[mi][ni] = __builtin_amdgcn_mfma_f32_16x16x32_bf16(
                    afrag[mi], bfrag[ni], acc[mi][ni], 0, 0, 0);
    }

    #pragma unroll
    for (int mi = 0; mi < 4; ++mi) {
        #pragma unroll
        for (int reg = 0; reg < 4; ++reg) {
            const int lrow = wm * 64 + mi * 16 + qr * 4 + reg;
            const int grow = m0 + lrow;
            const int t = tgt_s[lrow];
            float se = 0.f, sl = 0.f;
            #pragma unroll
            for (int ni = 0; ni < 4; ++ni) {
                float v = acc[mi][ni][reg];
                int gcol = n0 + wn * 64 + ni * 16 + cr;
                if (t == gcol) tgtlogit[grow] = v;
                se += __expf(v);
                sl += v;
            }
            #pragma unroll
            for (int st = 1; st < 16; st <<= 1) {
                se += __shfl_xor(se, st, 64);
                sl += __shfl_xor(sl, st, 64);
            }
            if (cr == 0) {
                atomicAdd(&sumexp[grow], se);
                atomicAdd(&sumlog[grow], sl);
            }
        }
    }
}

// One block, 8 waves: wave w reduces sequence w (512 tokens).
__global__ void dpo_finalize(const float* __restrict__ sumexp,
                             const float* __restrict__ sumlog,
                             const float* __restrict__ tgtlogit,
                             const int* __restrict__ target,
                             float* __restrict__ out)
{
    __shared__ float s_logp[8], s_sl[8];
    const int lane = threadIdx.x & 63;
    const int w    = threadIdx.x >> 6;

    float lp = 0.f, cnt = 0.f, sl = 0.f;
    #pragma unroll
    for (int i = 0; i < 8; ++i) {
        int t  = w * 512 + i * 64 + lane;
        int tg = target[t];
        if (tg != IGNORE_INDEX) {
            lp  += tgtlogit[t] - logf(sumexp[t]);
            cnt += 1.f;
        }
        sl += sumlog[t];
    }
    #pragma unroll
    for (int s = 1; s < 64; s <<= 1) {
        lp  += __shfl_xor(lp, s, 64);
        cnt += __shfl_xor(cnt, s, 64);
        sl  += __shfl_xor(sl, s, 64);
    }
    if (lane == 0) { s_logp[w] = lp / cnt; s_sl[w] = sl; }
    __syncthreads();

    if (threadIdx.x == 0) {
        float cm = 0.f, rm = 0.f, loss = 0.f;
        for (int i = 0; i < 4; ++i) { cm += s_sl[i]; rm += s_sl[4 + i]; }
        const float denom = 4.f * 512.f * 32000.f;
        cm /= denom; rm /= denom;
        for (int i = 0; i < 4; ++i) {
            float d = BETA * (s_logp[i] - s_logp[4 + i]);
            float l = (d > 0.f) ? log1pf(expf(-d)) : (-d + log1pf(expf(d)));
            loss += l;
        }
        loss *= 0.25f;
        out[0] = loss;
        for (int i = 0; i < 4; ++i) out[1 + i] = s_logp[i];
        for (int i = 0; i < 4; ++i) out[5 + i] = s_logp[4 + i];
        out[9]  = cm;
        out[10] = rm;
        out[11] = 0.f;
    }
}

extern "C" void kernel_launch(void* const* d_in, const int* in_sizes, int n_in,
                              void* d_out, int out_size, void* d_ws, size_t ws_size,
                              hipStream_t stream) {
    const float* x      = (const float*)d_in[0];   // (8,512,4096) fp32
    const float* wgt    = (const float*)d_in[1];   // (32000,4096) fp32
    const int*   target = (const int*)d_in[2];     // (8,512) int32
    float* out = (float*)d_out;

    // ws layout: [sumexp 4096][sumlog 4096][tgtlogit 4096] floats, then fp8 x, then fp8 w
    float* sumexp   = (float*)d_ws;
    float* sumlog   = sumexp + Mdim;
    float* tgtlogit = sumlog + Mdim;
    char*  base     = (char*)d_ws + 3 * Mdim * sizeof(float);            // 49152 B
    unsigned char* x8 = (unsigned char*)base;                            // 16,777,216 B
    unsigned char* w8 = x8 + (size_t)Mdim * Kdim;                        // 131,072,000 B

    const size_t ws_needed = 3 * Mdim * sizeof(float)
                           + (size_t)Mdim * Kdim
                           + (size_t)Ndim * Kdim;

    hipMemsetAsync(d_ws, 0, 2 * Mdim * sizeof(float), stream);   // zero atomic accumulators

    if (ws_size >= ws_needed) {
        const long nx4 = (long)Mdim * Kdim / 4;   //  4,194,304 float4s
        const long nw4 = (long)Ndim * Kdim / 4;   // 32,768,000 float4s
        // G11: cap grid ~2048 blocks, grid-stride the rest.
        int bx = (int)(((nx4 + 255) / 256) < 2048 ? ((nx4 + 255) / 256) : 2048);
        int bw = (int)(((nw4 + 255) / 256) < 2048 ? ((nw4 + 255) / 256) : 2048);
        cvt_f32_fp8<<<bx, 256, 0, stream>>>((const float4*)x,   (uint*)x8, nx4);
        cvt_f32_fp8<<<bw, 256, 0, stream>>>((const float4*)wgt, (uint*)w8, nw4);
        dpo_gemm_fp8<<<MT * NT, 256, 0, stream>>>(x8, w8, target, sumexp, sumlog, tgtlogit);
    } else {
        dpo_gemm_f32<<<MT * NT, 256, 0, stream>>>(x, wgt, target, sumexp, sumlog, tgtlogit);
    }
    dpo_finalize<<<1, 512, 0, stream>>>(sumexp, sumlog, tgtlogit, target, out);
}

// Round 2
// 1308.710 us; speedup vs baseline: 1.0761x; 1.0761x over previous
//
#include <hip/hip_runtime.h>
#include <hip/hip_bf16.h>
#include <math.h>

#define IGNORE_INDEX (-100)
#define BETA 0.1f

// Problem constants (B=8, S=512, H=4096, V=32000)
constexpr int Mdim = 8 * 512;   // 4096 tokens
constexpr int Kdim = 4096;      // hidden
constexpr int Ndim = 32000;     // vocab

// fp8 GEMM geometry: 256x256 tile, 8 waves (2M x 4N), per-wave 128x64, BK=128 (one mfma-K)
constexpr int BM2 = 256, BN2 = 256, BK8 = 128;
constexpr int MT2 = Mdim / BM2;   // 16 m-tiles
constexpr int NT2 = Ndim / BN2;   // 125 n-tiles
constexpr int NTILES = Kdim / BK8; // 32 K-tiles

// fallback geometry
constexpr int BM = 128, BN = 128;
constexpr int MT = Mdim / BM;   // 32
constexpr int NT = Ndim / BN;   // 250

typedef __bf16 bf16x8 __attribute__((ext_vector_type(8)));
typedef __bf16 bf16x4 __attribute__((ext_vector_type(4)));
typedef float  floatx4 __attribute__((ext_vector_type(4)));
typedef int    v8i __attribute__((ext_vector_type(8)));
typedef int    v4i __attribute__((ext_vector_type(4)));

#define GPTR(p) ((const __attribute__((address_space(1))) void*)(p))
#define LPTR(p) ((__attribute__((address_space(3))) void*)(p))

// fp32 -> fp8 e4m3 via HW v_cvt_pk_fp8_f32. Lane-contiguous float4 grid-stride.
__global__ void cvt_f32_fp8(const float4* __restrict__ src, uint* __restrict__ dst, long n4) {
    long stride = (long)gridDim.x * blockDim.x;
    for (long i = (long)blockIdx.x * blockDim.x + threadIdx.x; i < n4; i += stride) {
        float4 a = src[i];
        int r = __builtin_amdgcn_cvt_pk_fp8_f32(a.x, a.y, 0, false);
        r     = __builtin_amdgcn_cvt_pk_fp8_f32(a.z, a.w, r, true);
        dst[i] = (uint)r;
    }
}

// MX-fp8 GEMM (unit E8M0 scales) + fused softmax-stat epilogue.
// 256x256 tile, 8 waves, per-wave 128x64 output (8x4 16x16 frags).
// LDS double-buffered (2 x (32KB A + 32KB B) = 128 KB). One __syncthreads per K-tile:
// stage loads for tile t+1 are issued into slot s^1 BEFORE the compute of tile t, so the
// barrier's implicit vmcnt(0) drain happens after ~800 cy of ds_read+MFMA cover.
// LDS XOR-swizzle (verified in prior rounds): LDS[row][c] = G[row][c ^ (row&7)] in 16B
// chunks, applied on the GLOBAL address so global_load_lds's (uniform base + lane*16)
// destination stays linear/legal.
__global__ __launch_bounds__(512, 2)
void dpo_gemm_fp8(const unsigned char* __restrict__ x8, const unsigned char* __restrict__ w8,
                  const int* __restrict__ target,
                  float* __restrict__ sumexp, float* __restrict__ sumlog,
                  float* __restrict__ tgtlogit)
{
    __shared__ unsigned char Alds[2 * BM2 * BK8];   // 64 KB
    __shared__ unsigned char Blds[2 * BN2 * BK8];   // 64 KB
    __shared__ int tgt_s[BM2];

    const int tid  = threadIdx.x;
    const int lane = tid & 63;
    const int wid  = tid >> 6;        // 0..7
    const int wr   = wid >> 2;        // wave M-half (0..1) -> rows wr*128
    const int wc   = wid & 3;         // wave N-quarter (0..3) -> cols wc*64

    // XCD-aware bijective swizzle (nwg=2000 = 8*250), m-fastest for weight-strip locality.
    const int bid = blockIdx.x;
    const int swz = (bid & 7) * (MT2 * NT2 / 8) + (bid >> 3);
    const int m0  = (swz & (MT2 - 1)) * BM2;
    const int n0  = (swz / MT2) * BN2;

    if (tid < BM2) tgt_s[tid] = target[m0 + tid];

    floatx4 acc[8][4] = {};

    const int qr = lane >> 4;   // quad 0..3 (k-group)
    const int cr = lane & 15;   // row-in-frag

    // Staging geometry: wave w covers rows w*32..w*32+31 over 4 issues (8 rows each).
    // lane l -> row = base + (l>>3), global chunk = (l&7)^(l>>3)  [row&7 == l>>3].
    const int srow   = lane >> 3;
    const int schunk = (lane & 7) ^ srow;
    const unsigned char* xg = x8 + (size_t)(m0 + wid * 32 + srow) * Kdim + schunk * 16;
    const unsigned char* wg = w8 + (size_t)(n0 + wid * 32 + srow) * Kdim + schunk * 16;
    const int stage_base = wid * 32 * BK8;   // byte offset of this wave's 4KB region

    // Prologue: stage K-tile 0 into slot 0.
    #pragma unroll
    for (int i = 0; i < 4; ++i) {
        __builtin_amdgcn_global_load_lds(GPTR(xg + (size_t)i * 8 * Kdim),
                                         LPTR(Alds + stage_base + i * 1024), 16, 0, 0);
        __builtin_amdgcn_global_load_lds(GPTR(wg + (size_t)i * 8 * Kdim),
                                         LPTR(Blds + stage_base + i * 1024), 16, 0, 0);
    }
    __syncthreads();   // drains vmcnt(0): slot 0 ready

    // Fragment chunk swizzle: global k-chunks 2q,2q+1 live at LDS chunks (2q)^s,(2q+1)^s,
    // s = row&7 = cr&7.
    const int sx = cr & 7;
    const int c0 = (2 * qr) ^ sx;
    const int c1 = (2 * qr + 1) ^ sx;

    for (int t = 0; t < NTILES; ++t) {
        const int s = t & 1;
        const unsigned char* Asl = Alds + s * (BM2 * BK8);
        const unsigned char* Bsl = Blds + s * (BN2 * BK8);
        unsigned char* Asn = (unsigned char*)Alds + (s ^ 1) * (BM2 * BK8) + stage_base;
        unsigned char* Bsn = (unsigned char*)Blds + (s ^ 1) * (BN2 * BK8) + stage_base;

        // B fragments (all 4, reused across both M-halves)
        v8i bfrag[4];
        #pragma unroll
        for (int ni = 0; ni < 4; ++ni) {
            const int base = (wc * 64 + ni * 16 + cr) * BK8;
            v4i lo = *(const v4i*)&Bsl[base + c0 * 16];
            v4i hi = *(const v4i*)&Bsl[base + c1 * 16];
            bfrag[ni] = __builtin_shufflevector(lo, hi, 0, 1, 2, 3, 4, 5, 6, 7);
        }

        // Issue-early: stage A for tile t+1 into slot s^1 (no reader of s^1 this iter)
        if (t + 1 < NTILES) {
            const unsigned char* g = xg + (size_t)(t + 1) * BK8;
            #pragma unroll
            for (int i = 0; i < 4; ++i)
                __builtin_amdgcn_global_load_lds(GPTR(g + (size_t)i * 8 * Kdim),
                                                 LPTR(Asn + i * 1024), 16, 0, 0);
        }

        // A fragments, M-half 0
        v8i afrag[4];
        #pragma unroll
        for (int mi = 0; mi < 4; ++mi) {
            const int base = (wr * 128 + mi * 16 + cr) * BK8;
            v4i lo = *(const v4i*)&Asl[base + c0 * 16];
            v4i hi = *(const v4i*)&Asl[base + c1 * 16];
            afrag[mi] = __builtin_shufflevector(lo, hi, 0, 1, 2, 3, 4, 5, 6, 7);
        }

        if (t + 1 < NTILES) {
            const unsigned char* g = wg + (size_t)(t + 1) * BK8;
            #pragma unroll
            for (int i = 0; i < 4; ++i)
                __builtin_amdgcn_global_load_lds(GPTR(g + (size_t)i * 8 * Kdim),
                                                 LPTR(Bsn + i * 1024), 16, 0, 0);
        }

        __builtin_amdgcn_s_setprio(1);
        #pragma unroll
        for (int mi = 0; mi < 4; ++mi)
            #pragma unroll
            for (int ni = 0; ni < 4; ++ni)
                acc[mi][ni] = __builtin_amdgcn_mfma_scale_f32_16x16x128_f8f6f4(
                    afrag[mi], bfrag[ni], acc[mi][ni],
                    0, 0, 0, 0x7F7F7F7F, 0, 0x7F7F7F7F);
        __builtin_amdgcn_s_setprio(0);

        // A fragments, M-half 1
        #pragma unroll
        for (int mi = 0; mi < 4; ++mi) {
            const int base = (wr * 128 + 64 + mi * 16 + cr) * BK8;
            v4i lo = *(const v4i*)&Asl[base + c0 * 16];
            v4i hi = *(const v4i*)&Asl[base + c1 * 16];
            afrag[mi] = __builtin_shufflevector(lo, hi, 0, 1, 2, 3, 4, 5, 6, 7);
        }

        __builtin_amdgcn_s_setprio(1);
        #pragma unroll
        for (int mi = 0; mi < 4; ++mi)
            #pragma unroll
            for (int ni = 0; ni < 4; ++ni)
                acc[4 + mi][ni] = __builtin_amdgcn_mfma_scale_f32_16x16x128_f8f6f4(
                    afrag[mi], bfrag[ni], acc[4 + mi][ni],
                    0, 0, 0, 0x7F7F7F7F, 0, 0x7F7F7F7F);
        __builtin_amdgcn_s_setprio(0);

        // Single barrier per K-tile: drains this wave's stage loads (vmcnt 0) and its
        // ds_reads; after it, slot s^1 is fully staged for all waves and slot s is free.
        __syncthreads();
    }

    // Epilogue: C/D layout col=lane&15, row=(lane>>4)*4+reg (shape-determined).
    #pragma unroll
    for (int mi8 = 0; mi8 < 8; ++mi8) {
        #pragma unroll
        for (int reg = 0; reg < 4; ++reg) {
            const int lrow = wr * 128 + mi8 * 16 + qr * 4 + reg;
            const int grow = m0 + lrow;
            const int t = tgt_s[lrow];
            float se = 0.f, sl = 0.f;
            #pragma unroll
            for (int ni = 0; ni < 4; ++ni) {
                float v = acc[mi8][ni][reg];
                int gcol = n0 + wc * 64 + ni * 16 + cr;
                if (t == gcol) tgtlogit[grow] = v;   // unique owner globally
                se += __expf(v);
                sl += v;
            }
            #pragma unroll
            for (int st = 1; st < 16; st <<= 1) {
                se += __shfl_xor(se, st, 64);
                sl += __shfl_xor(sl, st, 64);
            }
            if (cr == 0) {
                atomicAdd(&sumexp[grow], se);
                atomicAdd(&sumlog[grow], sl);
            }
        }
    }
}

// Fallback (ws too small): fp32-staged bf16 GEMM.
__global__ __launch_bounds__(256, 2)
void dpo_gemm_f32(const float* __restrict__ x, const float* __restrict__ w,
                  const int* __restrict__ target,
                  float* __restrict__ sumexp, float* __restrict__ sumlog,
                  float* __restrict__ tgtlogit)
{
    constexpr int BK = 32;
    constexpr int LDA = 40;
    __shared__ __bf16 As[BM * LDA];
    __shared__ __bf16 Bs[BN * LDA];
    __shared__ int tgt_s[BM];

    const int tid  = threadIdx.x;
    const int lane = tid & 63;
    const int wid  = tid >> 6;
    const int wm   = wid & 1;
    const int wn   = wid >> 1;
    const int bid  = blockIdx.x;
    const int m0   = (bid & (MT - 1)) * BM;
    const int n0   = (bid / MT) * BN;

    if (tid < BM) tgt_s[tid] = target[m0 + tid];

    floatx4 acc[4][4] = {};
    const int qr = lane >> 4;
    const int cr = lane & 15;

    for (int k0 = 0; k0 < Kdim; k0 += BK) {
        __syncthreads();
        #pragma unroll
        for (int i = 0; i < 4; ++i) {
            int idx = tid + i * 256;
            int row = idx >> 3;
            int c4  = (idx & 7) * 4;
            float4 v = *(const float4*)(x + (size_t)(m0 + row) * Kdim + k0 + c4);
            bf16x4 p;
            p[0] = (__bf16)v.x; p[1] = (__bf16)v.y; p[2] = (__bf16)v.z; p[3] = (__bf16)v.w;
            *(bf16x4*)&As[row * LDA + c4] = p;
        }
        #pragma unroll
        for (int i = 0; i < 4; ++i) {
            int idx = tid + i * 256;
            int row = idx >> 3;
            int c4  = (idx & 7) * 4;
            float4 v = *(const float4*)(w + (size_t)(n0 + row) * Kdim + k0 + c4);
            bf16x4 p;
            p[0] = (__bf16)v.x; p[1] = (__bf16)v.y; p[2] = (__bf16)v.z; p[3] = (__bf16)v.w;
            *(bf16x4*)&Bs[row * LDA + c4] = p;
        }
        __syncthreads();

        bf16x8 afrag[4], bfrag[4];
        #pragma unroll
        for (int mi = 0; mi < 4; ++mi)
            afrag[mi] = *(const bf16x8*)&As[(wm * 64 + mi * 16 + cr) * LDA + qr * 8];
        #pragma unroll
        for (int ni = 0; ni < 4; ++ni)
            bfrag[ni] = *(const bf16x8*)&Bs[(wn * 64 + ni * 16 + cr) * LDA + qr * 8];

        #pragma unroll
        for (int mi = 0; mi < 4; ++mi)
            #pragma unroll
            for (int ni = 0; ni < 4; ++ni)
                acc[mi][ni] = __builtin_amdgcn_mfma_f32_16x16x32_bf16(
                    afrag[mi], bfrag[ni], acc[mi][ni], 0, 0, 0);
    }

    #pragma unroll
    for (int mi = 0; mi < 4; ++mi) {
        #pragma unroll
        for (int reg = 0; reg < 4; ++reg) {
            const int lrow = wm * 64 + mi * 16 + qr * 4 + reg;
            const int grow = m0 + lrow;
            const int t = tgt_s[lrow];
            float se = 0.f, sl = 0.f;
            #pragma unroll
            for (int ni = 0; ni < 4; ++ni) {
                float v = acc[mi][ni][reg];
                int gcol = n0 + wn * 64 + ni * 16 + cr;
                if (t == gcol) tgtlogit[grow] = v;
                se += __expf(v);
                sl += v;
            }
            #pragma unroll
            for (int st = 1; st < 16; st <<= 1) {
                se += __shfl_xor(se, st, 64);
                sl += __shfl_xor(sl, st, 64);
            }
            if (cr == 0) {
                atomicAdd(&sumexp[grow], se);
                atomicAdd(&sumlog[grow], sl);
            }
        }
    }
}

// One block, 8 waves: wave w reduces sequence w (512 tokens).
__global__ void dpo_finalize(const float* __restrict__ sumexp,
                             const float* __restrict__ sumlog,
                             const float* __restrict__ tgtlogit,
                             const int* __restrict__ target,
                             float* __restrict__ out)
{
    __shared__ float s_logp[8], s_sl[8];
    const int lane = threadIdx.x & 63;
    const int w    = threadIdx.x >> 6;

    float lp = 0.f, cnt = 0.f, sl = 0.f;
    #pragma unroll
    for (int i = 0; i < 8; ++i) {
        int t  = w * 512 + i * 64 + lane;
        int tg = target[t];
        if (tg != IGNORE_INDEX) {
            lp  += tgtlogit[t] - logf(sumexp[t]);
            cnt += 1.f;
        }
        sl += sumlog[t];
    }
    #pragma unroll
    for (int s = 1; s < 64; s <<= 1) {
        lp  += __shfl_xor(lp, s, 64);
        cnt += __shfl_xor(cnt, s, 64);
        sl  += __shfl_xor(sl, s, 64);
    }
    if (lane == 0) { s_logp[w] = lp / cnt; s_sl[w] = sl; }
    __syncthreads();

    if (threadIdx.x == 0) {
        float cm = 0.f, rm = 0.f, loss = 0.f;
        for (int i = 0; i < 4; ++i) { cm += s_sl[i]; rm += s_sl[4 + i]; }
        const float denom = 4.f * 512.f * 32000.f;
        cm /= denom; rm /= denom;
        for (int i = 0; i < 4; ++i) {
            float d = BETA * (s_logp[i] - s_logp[4 + i]);
            float l = (d > 0.f) ? log1pf(expf(-d)) : (-d + log1pf(expf(d)));
            loss += l;
        }
        loss *= 0.25f;
        out[0] = loss;
        for (int i = 0; i < 4; ++i) out[1 + i] = s_logp[i];
        for (int i = 0; i < 4; ++i) out[5 + i] = s_logp[4 + i];
        out[9]  = cm;
        out[10] = rm;
        out[11] = 0.f;
    }
}

extern "C" void kernel_launch(void* const* d_in, const int* in_sizes, int n_in,
                              void* d_out, int out_size, void* d_ws, size_t ws_size,
                              hipStream_t stream) {
    const float* x      = (const float*)d_in[0];   // (8,512,4096) fp32
    const float* wgt    = (const float*)d_in[1];   // (32000,4096) fp32
    const int*   target = (const int*)d_in[2];     // (8,512) int32
    float* out = (float*)d_out;

    float* sumexp   = (float*)d_ws;
    float* sumlog   = sumexp + Mdim;
    float* tgtlogit = sumlog + Mdim;
    char*  base     = (char*)d_ws + 3 * Mdim * sizeof(float);
    unsigned char* x8 = (unsigned char*)base;
    unsigned char* w8 = x8 + (size_t)Mdim * Kdim;

    const size_t ws_needed = 3 * Mdim * sizeof(float)
                           + (size_t)Mdim * Kdim
                           + (size_t)Ndim * Kdim;

    hipMemsetAsync(d_ws, 0, 2 * Mdim * sizeof(float), stream);

    if (ws_size >= ws_needed) {
        const long nx4 = (long)Mdim * Kdim / 4;
        const long nw4 = (long)Ndim * Kdim / 4;
        int bx = (int)(((nx4 + 255) / 256) < 2048 ? ((nx4 + 255) / 256) : 2048);
        int bw = (int)(((nw4 + 255) / 256) < 2048 ? ((nw4 + 255) / 256) : 2048);
        cvt_f32_fp8<<<bx, 256, 0, stream>>>((const float4*)x,   (uint*)x8, nx4);
        cvt_f32_fp8<<<bw, 256, 0, stream>>>((const float4*)wgt, (uint*)w8, nw4);
        dpo_gemm_fp8<<<MT2 * NT2, 512, 0, stream>>>(x8, w8, target, sumexp, sumlog, tgtlogit);
    } else {
        dpo_gemm_f32<<<MT * NT, 256, 0, stream>>>(x, wgt, target, sumexp, sumlog, tgtlogit);
    }
    dpo_finalize<<<1, 512, 0, stream>>>(sumexp, sumlog, tgtlogit, target, out);
}